// Round 10
// baseline (869.190 us; speedup 1.0000x reference)
//
#include <hip/hip_runtime.h>
#include <hip/hip_bf16.h>

// ModulatedConv2d b=16, ic=oc=512, k=3, h=w=64.
// R10: m201 8-phase port. 256x256 tile, BK=64, dbuf-2 (128KB), 8 waves.
// Per phase: {ds_reads, stage 1 half-tile (2xGLL), barrier, lgkmcnt(0),
// setprio+16 MFMA, barrier}; vmcnt(4) only at phases 4 & 8 (12-deep window).
// 8-slot XOR swizzle (col8 ^ row&7) on pre-swizzled global source. A offsets
// fully linear (fold to immediates); B pointers hoisted per tap.

typedef __bf16 bf16x8 __attribute__((ext_vector_type(8)));
typedef float  f32x4  __attribute__((ext_vector_type(4)));

#define IC   512
#define OC   512
#define HW   4096
#define KTOT 4608

typedef __attribute__((address_space(3))) unsigned lds_u32;
typedef const __attribute__((address_space(1))) unsigned glb_u32;
#define GLL16(gsrc, ldst) \
    __builtin_amdgcn_global_load_lds((glb_u32*)(gsrc), (lds_u32*)(ldst), 16, 0, 0)
#define BAR()   asm volatile("s_barrier" ::: "memory")
#define LGKM0() asm volatile("s_waitcnt lgkmcnt(0)" ::: "memory")

template<int N> __device__ __forceinline__ void vmw() {
    asm volatile("s_waitcnt vmcnt(%0)" :: "n"(N) : "memory");
}

// ---------------- kernel 1: style modulation s[b][i] ----------------
__global__ __launch_bounds__(256) void style_mod_kernel(
    const float* __restrict__ style, const float* __restrict__ mod_w,
    const float* __restrict__ mod_b, float* __restrict__ s_out)
{
    int pair = blockIdx.x * 4 + (threadIdx.x >> 6);
    int lane = threadIdx.x & 63;
    int b = pair >> 9;
    int i = pair & 511;
    const float4* sv = (const float4*)(style + b * 512);
    const float4* wv = (const float4*)(mod_w + i * 512);
    float4 a0 = sv[lane * 2], a1 = sv[lane * 2 + 1];
    float4 w0 = wv[lane * 2], w1 = wv[lane * 2 + 1];
    float sum = a0.x*w0.x + a0.y*w0.y + a0.z*w0.z + a0.w*w0.w
              + a1.x*w1.x + a1.y*w1.y + a1.z*w1.z + a1.w*w1.w;
    #pragma unroll
    for (int off = 32; off; off >>= 1) sum += __shfl_xor(sum, off);
    if (lane == 0) s_out[pair] = sum + mod_b[i];
}

// ------------- kernel 2: demod + bf16 wmod, block per oc -------------
// demod_b = rsqrt(sum_ic q[ic]*s[b,ic]^2 + eps), q[ic] = sum_tap w^2.
// Reads weight ONCE (9.4MB, was 150MB effective).
__global__ __launch_bounds__(256) void wmod_kernel(
    const float* __restrict__ weight,   // [512][4608] (e = ic*9+tap)
    const float* __restrict__ s_in,     // [16][512]
    __hip_bfloat16* __restrict__ wmod)  // [16*512][4608] (e' = tap*512+ic)
{
    int oc = blockIdx.x;
    __shared__ float w_sh[4608];
    __shared__ float s_sh[8192];
    __shared__ float q_sh[512];
    __shared__ float demod_sh[16];
    int t = threadIdx.x;
    const float* wrow = weight + (size_t)oc * KTOT;
    for (int e = t; e < 4608; e += 256) w_sh[e] = wrow[e];
    for (int e = t; e < 8192; e += 256) s_sh[e] = s_in[e];
    __syncthreads();
    for (int ic = t; ic < 512; ic += 256) {
        float q = 0.f;
        #pragma unroll
        for (int tap = 0; tap < 9; ++tap) { float w = w_sh[ic * 9 + tap]; q += w * w; }
        q_sh[ic] = q;
    }
    __syncthreads();
    int bb = t >> 4, li = t & 15;
    float part = 0.f;
    for (int ic = li; ic < 512; ic += 16) {
        float sv = s_sh[bb * 512 + ic];
        part += q_sh[ic] * sv * sv;
    }
    #pragma unroll
    for (int off = 8; off; off >>= 1) part += __shfl_xor(part, off, 16);
    if (li == 0) demod_sh[bb] = rsqrtf(part + 1e-8f);
    __syncthreads();
    for (int b2 = 0; b2 < 16; ++b2) {
        float dm = demod_sh[b2];
        const float* srow = s_sh + b2 * 512;
        __hip_bfloat16* dst = wmod + ((size_t)b2 * 512 + oc) * KTOT;
        for (int ep = t; ep < 4608; ep += 256) {
            int tap = ep >> 9, ic = ep & 511;
            dst[ep] = __float2bfloat16(w_sh[ic * 9 + tap] * srow[ic] * dm);
        }
    }
}

// ------------- kernel 3a: zero pad row of xT -------------
__global__ void zero_row_kernel(__hip_bfloat16* xT) {
    ((unsigned*)(xT + ((size_t)blockIdx.x * 4097 + 4096) * 512))[threadIdx.x] = 0u;
}

// ------------- kernel 3b: x [b][ic][pix] f32 -> xT [b][pix][ic] bf16 -------------
__global__ __launch_bounds__(256) void xpose_kernel(
    const float* __restrict__ x, __hip_bfloat16* __restrict__ xT)
{
    __shared__ __align__(16) float tile[64][68];
    int b = blockIdx.z, ic0 = blockIdx.y * 64, p0 = blockIdx.x * 64;
    int t = threadIdx.x;
    const float* xb = x + ((size_t)b * 512 + ic0) * 4096 + p0;
    int rr = t >> 4, cc = (t & 15) * 4;
    #pragma unroll
    for (int i = 0; i < 4; ++i) {
        float4 v = *(const float4*)(xb + (size_t)(rr + i * 16) * 4096 + cc);
        *(float4*)&tile[rr + i * 16][cc] = v;
    }
    __syncthreads();
    int pr = t >> 2, io = (t & 3) * 16;
    __hip_bfloat16 obuf[16];
    #pragma unroll
    for (int j = 0; j < 16; ++j) obuf[j] = __float2bfloat16(tile[io + j][pr]);
    __hip_bfloat16* dst = xT + ((size_t)b * 4097 + p0 + pr) * 512 + ic0 + io;
    *(uint4*)dst       = *(uint4*)&obuf[0];
    *(uint4*)(dst + 8) = *(uint4*)&obuf[8];
}

// ------------- kernel 4: conv, 256x256 BK=64 dbuf-2, 8-phase -------------
__global__ __launch_bounds__(512, 2) void conv_kernel(
    const __hip_bfloat16* __restrict__ xT,    // [16][4097][512]
    const __hip_bfloat16* __restrict__ wmod,  // [16*512][4608]
    const float* __restrict__ bias,
    float* __restrict__ out)                  // [16][512][4096]
{
    __shared__ __align__(16) __hip_bfloat16 Ash[2][256 * 64];   // 64 KB
    __shared__ __align__(16) __hip_bfloat16 Bsh[2][256 * 64];   // 64 KB
    __hip_bfloat16* const Ash0 = &Ash[0][0];
    __hip_bfloat16* const Ash1 = &Ash[1][0];
    __hip_bfloat16* const Bsh0 = &Bsh[0][0];
    __hip_bfloat16* const Bsh1 = &Bsh[1][0];

    const int t    = threadIdx.x;
    const int lane = t & 63;
    const int wid  = t >> 6;      // 0..7
    const int wm   = wid >> 2;    // 0..1 (M half: 128 oc rows)
    const int wn   = wid & 3;     // 0..3 (N quarter: 64 px)
    const int lr   = lane & 15;
    const int lq   = lane >> 4;

    // block decode: 512 blocks; per XCD 2 b's; oc-tile inner (B panel L2 reuse)
    int bid = blockIdx.x;
    int xcd = bid & 7, idx = bid >> 3;
    int oc1 = idx & 1;
    int nt  = (idx >> 1) & 15;
    int bb  = (idx >> 5) & 1;
    int b   = xcd * 2 + bb;
    int oc0 = oc1 * 256, n0 = nt * 256;

    const __hip_bfloat16* wb = wmod + (size_t)(b * 512 + oc0) * KTOT;
    const __hip_bfloat16* xb = xT + (size_t)b * 4097 * 512;

    // stage geometry: tile [256 rows][64 k]; unit u (16B): row u>>3, phys col8
    // u&7; swizzle: slot holds logical col8 = (u&7) ^ (row&7). Thread t owns
    // units t+512j (rows (t>>3)+64j; row&7 invariant) -> one qoff per thread.
    const int qoff = (((t & 7) ^ ((t >> 3) & 7)) * 8);
    const int srow = t >> 3;                  // 0..63
    const int p0g  = n0 + srow;
    const int y0p  = p0g >> 6, x0p = p0g & 63;

    const __hip_bfloat16* pA0 = wb + (size_t)srow * KTOT + qoff;
    const __hip_bfloat16* pA1 = pA0 + (size_t)64  * KTOT;
    const __hip_bfloat16* pA2 = pA0 + (size_t)128 * KTOT;
    const __hip_bfloat16* pA3 = pA0 + (size_t)192 * KTOT;

    // fragment-read bases: row*64 + ((kc*4+lq)^(row&7))*8, row&7 == lr&7
    const int aoff0 = (wm * 128 + lr) * 64 + ((lq       ^ (lr & 7)) * 8);
    const int aoff1 = (wm * 128 + lr) * 64 + (((4 + lq) ^ (lr & 7)) * 8);
    const int boff0 = (wn * 64  + lr) * 64 + ((lq       ^ (lr & 7)) * 8);
    const int boff1 = (wn * 64  + lr) * 64 + (((4 + lq) ^ (lr & 7)) * 8);

    f32x4 acc[8][4] = {};
    bf16x8 a0[8], a1[8], b0[4], b1[4];

    // per-tap B stage pointers, rows srow+{0,64,128,192} (= +{0,1,2,3} img rows)
    const __hip_bfloat16 *pB0_, *pB1_, *pB2_, *pB3_, *nB0, *nB1, *nB2, *nB3;
    auto bptrs = [&](int tap, const __hip_bfloat16*& P0, const __hip_bfloat16*& P1,
                     const __hip_bfloat16*& P2, const __hip_bfloat16*& P3) {
        int dy = tap / 3 - 1, dx = tap % 3 - 1;
        int sx = x0p + dx;
        bool okx = ((unsigned)sx < 64u);
        int sy0 = y0p + dy;
        int q0 = (okx & ((unsigned)(sy0    ) < 64u)) ? ((sy0    ) * 64 + sx) : 4096;
        int q1 = (okx & ((unsigned)(sy0 + 1) < 64u)) ? ((sy0 + 1) * 64 + sx) : 4096;
        int q2 = (okx & ((unsigned)(sy0 + 2) < 64u)) ? ((sy0 + 2) * 64 + sx) : 4096;
        int q3 = (okx & ((unsigned)(sy0 + 3) < 64u)) ? ((sy0 + 3) * 64 + sx) : 4096;
        P0 = xb + (size_t)q0 * 512 + qoff;
        P1 = xb + (size_t)q1 * 512 + qoff;
        P2 = xb + (size_t)q2 * 512 + qoff;
        P3 = xb + (size_t)q3 * 512 + qoff;
    };

#define MF16(M0, AF, BF) { \
    __builtin_amdgcn_s_setprio(1); \
    _Pragma("unroll") for (int mi = 0; mi < 4; ++mi) \
        _Pragma("unroll") for (int ni = 0; ni < 4; ++ni) \
            acc[(M0) + mi][ni] = __builtin_amdgcn_mfma_f32_16x16x32_bf16( \
                AF[(M0) + mi], BF[ni], acc[(M0) + mi][ni], 0, 0, 0); \
    __builtin_amdgcn_s_setprio(0); }

// iter = 2 k-tiles (t0->buf0, t1->buf1); stages: B(t1)@ph1-2, A(s0)@ph3-4,
// B(s0)@ph5-6, A(s1)@ph7-8. vmcnt(4) at ph4 & ph8. TAIL: only B(t1), vmcnt(0).
#define ITER_BODY(CT1, SCA, SCB, SP0, SP1, SP2, SP3, TAIL, VN4) { \
    /* ph1 */ \
    _Pragma("unroll") for (int mi = 0; mi < 8; ++mi) a0[mi] = *(const bf16x8*)&Ash0[aoff0 + mi * 1024]; \
    _Pragma("unroll") for (int ni = 0; ni < 4; ++ni) b0[ni] = *(const bf16x8*)&Bsh0[boff0 + ni * 1024]; \
    GLL16(pB0_ + (CT1), &Bsh1[t * 8]); GLL16(pB1_ + (CT1), &Bsh1[(t + 512) * 8]); \
    BAR(); LGKM0(); \
    MF16(0, a0, b0); \
    BAR(); \
    /* ph2 */ \
    _Pragma("unroll") for (int mi = 0; mi < 8; ++mi) a1[mi] = *(const bf16x8*)&Ash0[aoff1 + mi * 1024]; \
    GLL16(pB2_ + (CT1), &Bsh1[(t + 1024) * 8]); GLL16(pB3_ + (CT1), &Bsh1[(t + 1536) * 8]); \
    BAR(); LGKM0(); \
    MF16(4, a0, b0); \
    BAR(); \
    /* ph3 */ \
    _Pragma("unroll") for (int ni = 0; ni < 4; ++ni) b1[ni] = *(const bf16x8*)&Bsh0[boff1 + ni * 1024]; \
    if (!(TAIL)) { GLL16(pA0 + (SCA), &Ash0[t * 8]); GLL16(pA1 + (SCA), &Ash0[(t + 512) * 8]); } \
    BAR(); LGKM0(); \
    MF16(0, a1, b1); \
    BAR(); \
    /* ph4 */ \
    if (!(TAIL)) { GLL16(pA2 + (SCA), &Ash0[(t + 1024) * 8]); GLL16(pA3 + (SCA), &Ash0[(t + 1536) * 8]); } \
    BAR(); \
    MF16(4, a1, b1); \
    vmw<VN4>(); \
    BAR(); \
    /* ph5 */ \
    _Pragma("unroll") for (int mi = 0; mi < 8; ++mi) a0[mi] = *(const bf16x8*)&Ash1[aoff0 + mi * 1024]; \
    _Pragma("unroll") for (int ni = 0; ni < 4; ++ni) b0[ni] = *(const bf16x8*)&Bsh1[boff0 + ni * 1024]; \
    if (!(TAIL)) { GLL16((SP0) + (SCB), &Bsh0[t * 8]); GLL16((SP1) + (SCB), &Bsh0[(t + 512) * 8]); } \
    BAR(); LGKM0(); \
    MF16(0, a0, b0); \
    BAR(); \
    /* ph6 */ \
    _Pragma("unroll") for (int mi = 0; mi < 8; ++mi) a1[mi] = *(const bf16x8*)&Ash1[aoff1 + mi * 1024]; \
    if (!(TAIL)) { GLL16((SP2) + (SCB), &Bsh0[(t + 1024) * 8]); GLL16((SP3) + (SCB), &Bsh0[(t + 1536) * 8]); } \
    BAR(); LGKM0(); \
    MF16(4, a0, b0); \
    BAR(); \
    /* ph7 */ \
    _Pragma("unroll") for (int ni = 0; ni < 4; ++ni) b1[ni] = *(const bf16x8*)&Bsh1[boff1 + ni * 1024]; \
    if (!(TAIL)) { GLL16(pA0 + (SCA) + 64, &Ash1[t * 8]); GLL16(pA1 + (SCA) + 64, &Ash1[(t + 512) * 8]); } \
    BAR(); LGKM0(); \
    MF16(0, a1, b1); \
    BAR(); \
    /* ph8 */ \
    if (!(TAIL)) { GLL16(pA2 + (SCA) + 64, &Ash1[(t + 1024) * 8]); GLL16(pA3 + (SCA) + 64, &Ash1[(t + 1536) * 8]); } \
    BAR(); \
    MF16(4, a1, b1); \
    if (!(TAIL)) { vmw<4>(); } \
    BAR(); \
}

    // ---- prologue: A(0), B(0), A(1); tile0 resident, A(1) 4 in flight ----
    bptrs(0, pB0_, pB1_, pB2_, pB3_);
    GLL16(pA0, &Ash0[t * 8]);            GLL16(pA1, &Ash0[(t + 512) * 8]);
    GLL16(pA2, &Ash0[(t + 1024) * 8]);   GLL16(pA3, &Ash0[(t + 1536) * 8]);
    GLL16(pB0_, &Bsh0[t * 8]);           GLL16(pB1_, &Bsh0[(t + 512) * 8]);
    GLL16(pB2_, &Bsh0[(t + 1024) * 8]);  GLL16(pB3_, &Bsh0[(t + 1536) * 8]);
    GLL16(pA0 + 64, &Ash1[t * 8]);          GLL16(pA1 + 64, &Ash1[(t + 512) * 8]);
    GLL16(pA2 + 64, &Ash1[(t + 1024) * 8]); GLL16(pA3 + 64, &Ash1[(t + 1536) * 8]);
    vmw<4>();
    BAR();

    for (int T = 0; T < 9; ++T) {
        ITER_BODY( 64, 128, 128, pB0_, pB1_, pB2_, pB3_, false, 4);
        ITER_BODY(192, 256, 256, pB0_, pB1_, pB2_, pB3_, false, 4);
        ITER_BODY(320, 384, 384, pB0_, pB1_, pB2_, pB3_, false, 4);
        if (T < 8) {
            bptrs(T + 1, nB0, nB1, nB2, nB3);
            ITER_BODY(448, 512, 0, nB0, nB1, nB2, nB3, false, 4);
            pA0 += 512; pA1 += 512; pA2 += 512; pA3 += 512;
            pB0_ = nB0; pB1_ = nB1; pB2_ = nB2; pB3_ = nB3;
        } else {
            ITER_BODY(448, 0, 0, pB0_, pB1_, pB2_, pB3_, true, 0);
        }
    }
#undef ITER_BODY
#undef MF16

    // ---- epilogue ----
    #pragma unroll
    for (int mi = 0; mi < 8; ++mi) {
        int oc = oc0 + wm * 128 + mi * 16 + lq * 4;
        #pragma unroll
        for (int ni = 0; ni < 4; ++ni) {
            int n = n0 + wn * 64 + ni * 16 + lr;
            #pragma unroll
            for (int v = 0; v < 4; ++v) {
                float r = acc[mi][ni][v] + bias[oc + v];
                out[((size_t)(b * OC + oc + v)) * HW + n] = r;
            }
        }
    }
}

extern "C" void kernel_launch(void* const* d_in, const int* in_sizes, int n_in,
                              void* d_out, int out_size, void* d_ws, size_t ws_size,
                              hipStream_t stream) {
    const float* x      = (const float*)d_in[0];
    const float* style  = (const float*)d_in[1];
    const float* weight = (const float*)d_in[2];
    const float* bias   = (const float*)d_in[3];
    const float* mod_w  = (const float*)d_in[4];
    const float* mod_b  = (const float*)d_in[5];
    float* out = (float*)d_out;

    // ws: s [32KB] | wmod bf16 [75.5MB] | xT bf16 [67.2MB]
    float* s_ws = (float*)d_ws;
    __hip_bfloat16* wmod = (__hip_bfloat16*)((char*)d_ws + 32768);
    __hip_bfloat16* xT   = (__hip_bfloat16*)((char*)d_ws + 32768 + (size_t)16 * 512 * KTOT * 2);

    style_mod_kernel<<<2048, 256, 0, stream>>>(style, mod_w, mod_b, s_ws);
    wmod_kernel<<<512, 256, 0, stream>>>(weight, s_ws, wmod);
    zero_row_kernel<<<16, 256, 0, stream>>>(xT);
    dim3 tgrid(64, 8, 16);
    xpose_kernel<<<tgrid, 256, 0, stream>>>(x, xT);
    conv_kernel<<<512, 512, 0, stream>>>(xT, wmod, bias, out);
}

// Round 11
// 338.956 us; speedup vs baseline: 2.5643x; 2.5643x over previous
//
#include <hip/hip_runtime.h>
#include <hip/hip_bf16.h>

// ModulatedConv2d b=16, ic=oc=512, k=3, h=w=64.
// R11: conv = R6 kernel exactly (best measured: 310us conv, MfmaUtil 44.5%,
// 0 bank conflicts, FETCH 268MB): 256x256 tile, BK=32, LDS ring-4, stage 3
// steps ahead, counted vmcnt(8) EVERY step (keeps blocks K-synced -> L2 reuse),
// involution swizzle, 2-phase split, setprio.
// wmod = R10's block-per-oc rewrite (reads weight once: 9.4MB vs ~150MB).

typedef __bf16 bf16x8 __attribute__((ext_vector_type(8)));
typedef float  f32x4  __attribute__((ext_vector_type(4)));

#define IC   512
#define OC   512
#define HW   4096
#define KTOT 4608

typedef __attribute__((address_space(3))) unsigned lds_u32;
typedef const __attribute__((address_space(1))) unsigned glb_u32;
#define GLL16(gsrc, ldst) \
    __builtin_amdgcn_global_load_lds((glb_u32*)(gsrc), (lds_u32*)(ldst), 16, 0, 0)
#define VMW(N)  asm volatile("s_waitcnt vmcnt(" #N ")" ::: "memory")
#define BAR()   asm volatile("s_barrier" ::: "memory")
#define SCHED0() __builtin_amdgcn_sched_barrier(0)

// ---------------- kernel 1: style modulation s[b][i] ----------------
__global__ __launch_bounds__(256) void style_mod_kernel(
    const float* __restrict__ style, const float* __restrict__ mod_w,
    const float* __restrict__ mod_b, float* __restrict__ s_out)
{
    int pair = blockIdx.x * 4 + (threadIdx.x >> 6);
    int lane = threadIdx.x & 63;
    int b = pair >> 9;
    int i = pair & 511;
    const float4* sv = (const float4*)(style + b * 512);
    const float4* wv = (const float4*)(mod_w + i * 512);
    float4 a0 = sv[lane * 2], a1 = sv[lane * 2 + 1];
    float4 w0 = wv[lane * 2], w1 = wv[lane * 2 + 1];
    float sum = a0.x*w0.x + a0.y*w0.y + a0.z*w0.z + a0.w*w0.w
              + a1.x*w1.x + a1.y*w1.y + a1.z*w1.z + a1.w*w1.w;
    #pragma unroll
    for (int off = 32; off; off >>= 1) sum += __shfl_xor(sum, off);
    if (lane == 0) s_out[pair] = sum + mod_b[i];
}

// ------------- kernel 2: demod + bf16 wmod, block per oc -------------
// demod_b = rsqrt(sum_ic q[ic]*s[b,ic]^2 + eps), q[ic] = sum_tap w^2.
// Reads weight ONCE (9.4MB); writes wmod[b][oc][tap*512+ic].
__global__ __launch_bounds__(256) void wmod_kernel(
    const float* __restrict__ weight,   // [512][4608] (e = ic*9+tap)
    const float* __restrict__ s_in,     // [16][512]
    __hip_bfloat16* __restrict__ wmod)  // [16*512][4608] (e' = tap*512+ic)
{
    int oc = blockIdx.x;
    __shared__ float w_sh[4608];
    __shared__ float s_sh[8192];
    __shared__ float q_sh[512];
    __shared__ float demod_sh[16];
    int t = threadIdx.x;
    const float* wrow = weight + (size_t)oc * KTOT;
    for (int e = t; e < 4608; e += 256) w_sh[e] = wrow[e];
    for (int e = t; e < 8192; e += 256) s_sh[e] = s_in[e];
    __syncthreads();
    for (int ic = t; ic < 512; ic += 256) {
        float q = 0.f;
        #pragma unroll
        for (int tap = 0; tap < 9; ++tap) { float w = w_sh[ic * 9 + tap]; q += w * w; }
        q_sh[ic] = q;
    }
    __syncthreads();
    int bb = t >> 4, li = t & 15;
    float part = 0.f;
    for (int ic = li; ic < 512; ic += 16) {
        float sv = s_sh[bb * 512 + ic];
        part += q_sh[ic] * sv * sv;
    }
    #pragma unroll
    for (int off = 8; off; off >>= 1) part += __shfl_xor(part, off, 16);
    if (li == 0) demod_sh[bb] = rsqrtf(part + 1e-8f);
    __syncthreads();
    for (int b2 = 0; b2 < 16; ++b2) {
        float dm = demod_sh[b2];
        const float* srow = s_sh + b2 * 512;
        __hip_bfloat16* dst = wmod + ((size_t)b2 * 512 + oc) * KTOT;
        for (int ep = t; ep < 4608; ep += 256) {
            int tap = ep >> 9, ic = ep & 511;
            dst[ep] = __float2bfloat16(w_sh[ic * 9 + tap] * srow[ic] * dm);
        }
    }
}

// ------------- kernel 3a: zero pad row of xT -------------
__global__ void zero_row_kernel(__hip_bfloat16* xT) {
    ((unsigned*)(xT + ((size_t)blockIdx.x * 4097 + 4096) * 512))[threadIdx.x] = 0u;
}

// ------------- kernel 3b: x [b][ic][pix] f32 -> xT [b][pix][ic] bf16 -------------
__global__ __launch_bounds__(256) void xpose_kernel(
    const float* __restrict__ x, __hip_bfloat16* __restrict__ xT)
{
    __shared__ __align__(16) float tile[64][68];
    int b = blockIdx.z, ic0 = blockIdx.y * 64, p0 = blockIdx.x * 64;
    int t = threadIdx.x;
    const float* xb = x + ((size_t)b * 512 + ic0) * 4096 + p0;
    int rr = t >> 4, cc = (t & 15) * 4;
    #pragma unroll
    for (int i = 0; i < 4; ++i) {
        float4 v = *(const float4*)(xb + (size_t)(rr + i * 16) * 4096 + cc);
        *(float4*)&tile[rr + i * 16][cc] = v;
    }
    __syncthreads();
    int pr = t >> 2, io = (t & 3) * 16;
    __hip_bfloat16 obuf[16];
    #pragma unroll
    for (int j = 0; j < 16; ++j) obuf[j] = __float2bfloat16(tile[io + j][pr]);
    __hip_bfloat16* dst = xT + ((size_t)b * 4097 + p0 + pr) * 512 + ic0 + io;
    *(uint4*)dst       = *(uint4*)&obuf[0];
    *(uint4*)(dst + 8) = *(uint4*)&obuf[8];
}

// ------------- kernel 4: conv, 256x256 ring-4, 2-phase interleave (R6) -------------
__global__ __launch_bounds__(512, 2) void conv_kernel(
    const __hip_bfloat16* __restrict__ xT,    // [16][4097][512]
    const __hip_bfloat16* __restrict__ wmod,  // [16*512][4608]
    const float* __restrict__ bias,
    float* __restrict__ out)                  // [16][512][4096]
{
    __shared__ __align__(16) __hip_bfloat16 Ash[4][256 * 32];
    __shared__ __align__(16) __hip_bfloat16 Bsh[4][256 * 32];

    const int t    = threadIdx.x;
    const int lane = t & 63;
    const int wid  = t >> 6;      // 0..7
    const int wm   = wid >> 2;    // 0..1 (M half)
    const int wn   = wid & 3;     // 0..3 (N quarter)
    const int lr   = lane & 15;
    const int lq   = lane >> 4;

    // block decode: 512 blocks; per XCD 2 b's; oc-tile inner (B-panel L2 reuse)
    int bid = blockIdx.x;
    int xcd = bid & 7, idx = bid >> 3;
    int oc1 = idx & 1;
    int nt  = (idx >> 1) & 15;
    int bb  = (idx >> 5) & 1;
    int b   = xcd * 2 + bb;
    int oc0 = oc1 * 256, n0 = nt * 256;

    const __hip_bfloat16* wb = wmod + (size_t)(b * 512 + oc0) * KTOT;
    const __hip_bfloat16* xb = xT + (size_t)b * 4097 * 512;

    // stage geometry: slot u (t, t+512): row u>>2, phys quad u&3.
    // involution swizzle (verified 0 conflicts): logical quad = (u&3)^((u>>3)&3).
    const int qoff = (((t & 3) ^ ((t >> 3) & 3)) * 8);
    const int srow = t >> 2;                 // 0..127 (second slot: +128)
    const int p0g  = n0 + srow;
    const int y0p  = p0g >> 6, x0p = p0g & 63;

    const __hip_bfloat16* pA0 = wb + (size_t)srow * KTOT + qoff;
    const __hip_bfloat16* pA1 = pA0 + (size_t)128 * KTOT;

    // fragment-read bases with matching swizzle
    const int swq = (lq ^ ((lr >> 1) & 3)) * 8;
    const int arb = (wm * 128 + lr) * 32 + swq;
    const int brb = (wn * 64  + lr) * 32 + swq;

    f32x4 acc[8][4] = {};

    // per-tap B row pointers (pixel shifted by (dy,dx); OOB -> zero row 4096)
    auto bptrs = [&](int tap, const __hip_bfloat16*& P0, const __hip_bfloat16*& P1) {
        int dy = tap / 3 - 1, dx = tap % 3 - 1;
        int sy = y0p + dy, sx = x0p + dx;
        int pix0 = ((((unsigned)sy)  < 64u) & (((unsigned)sx) < 64u)) ? ((sy  << 6) + sx) : 4096;
        int sy1 = sy + 2;   // second slot is +128 pixels = +2 image rows
        int pix1 = ((((unsigned)sy1) < 64u) & (((unsigned)sx) < 64u)) ? ((sy1 << 6) + sx) : 4096;
        P0 = xb + (size_t)pix0 * 512 + qoff;
        P1 = xb + (size_t)pix1 * 512 + qoff;
    };

#define STAGE_A(SB, OFF) { \
    GLL16(pA0 + (OFF), &Ash[SB][t * 8]); \
    GLL16(pA1 + (OFF), &Ash[SB][(t + 512) * 8]); }
#define STAGE_B(SB, Q0, Q1, OFF) { \
    GLL16((Q0) + (OFF), &Bsh[SB][t * 8]); \
    GLL16((Q1) + (OFF), &Bsh[SB][(t + 512) * 8]); }

#define MFMA_HALF(MB) { \
    __builtin_amdgcn_s_setprio(1); \
    _Pragma("unroll") for (int mi = 0; mi < 4; ++mi) \
        _Pragma("unroll") for (int ni = 0; ni < 4; ++ni) \
            acc[(MB) + mi][ni] = __builtin_amdgcn_mfma_f32_16x16x32_bf16( \
                af[mi], bfr[ni], acc[(MB) + mi][ni], 0, 0, 0); \
    __builtin_amdgcn_s_setprio(0); }

    const __hip_bfloat16 *pB0, *pB1, *nB0, *nB1;
    bptrs(0, pB0, pB1);

    // prologue: stage chunks 0,1,2 into ring 0,1,2 (all tap 0)
    STAGE_A(0, 0);  STAGE_B(0, pB0, pB1, 0);
    STAGE_A(1, 32); STAGE_B(1, pB0, pB1, 32);
    STAGE_A(2, 64); STAGE_B(2, pB0, pB1, 64);
    VMW(8);          // tile 0 resident (tiles 1,2 may fly)
    BAR();

    for (int tap = 0; tap < 8; ++tap) {
        bptrs(tap + 1, nB0, nB1);
        #pragma unroll
        for (int ch = 0; ch < 16; ++ch) {
            const int cb = ch & 3, sb = (ch + 3) & 3;
            bf16x8 af[4], bfr[4];
            // ---- phase 0: read A-low + all B frags; stage next A ----
            #pragma unroll
            for (int mi = 0; mi < 4; ++mi)
                af[mi] = *(const bf16x8*)(&Ash[cb][arb + mi * 512]);
            #pragma unroll
            for (int ni = 0; ni < 4; ++ni)
                bfr[ni] = *(const bf16x8*)(&Bsh[cb][brb + ni * 512]);
            STAGE_A(sb, (ch + 3) * 32);   // (16+c)*32 = 512+c*32 spans into next tap: exact
            BAR(); SCHED0();
            MFMA_HALF(0);
            BAR();
            // ---- phase 1: read A-high; stage next B ----
            #pragma unroll
            for (int mi = 0; mi < 4; ++mi)
                af[mi] = *(const bf16x8*)(&Ash[cb][arb + (4 + mi) * 512]);
            if (ch < 13) { STAGE_B(sb, pB0, pB1, (ch + 3) * 32); }
            else         { STAGE_B(sb, nB0, nB1, (ch - 13) * 32); }
            BAR(); SCHED0();
            MFMA_HALF(4);
            VMW(8);      // tile kk+1 resident; kk+2,kk+3 may fly
            BAR();
        }
        pA0 += 512; pA1 += 512;
        pB0 = nB0; pB1 = nB1;
    }
    // tap 8 (last): stage only while target chunk <= 143 (ch <= 12)
    #pragma unroll
    for (int ch = 0; ch < 16; ++ch) {
        const int cb = ch & 3, sb = (ch + 3) & 3;
        bf16x8 af[4], bfr[4];
        #pragma unroll
        for (int mi = 0; mi < 4; ++mi)
            af[mi] = *(const bf16x8*)(&Ash[cb][arb + mi * 512]);
        #pragma unroll
        for (int ni = 0; ni < 4; ++ni)
            bfr[ni] = *(const bf16x8*)(&Bsh[cb][brb + ni * 512]);
        if (ch <= 12) STAGE_A(sb, (ch + 3) * 32);
        BAR(); SCHED0();
        MFMA_HALF(0);
        BAR();
        #pragma unroll
        for (int mi = 0; mi < 4; ++mi)
            af[mi] = *(const bf16x8*)(&Ash[cb][arb + (4 + mi) * 512]);
        if (ch <= 12) STAGE_B(sb, pB0, pB1, (ch + 3) * 32);
        BAR(); SCHED0();
        MFMA_HALF(4);
        if      (ch < 13)  { VMW(8); BAR(); }
        else if (ch == 13) { VMW(4); BAR(); }
        else if (ch == 14) { VMW(0); BAR(); }
        // ch == 15: last compute, fall through to epilogue
    }
#undef STAGE_A
#undef STAGE_B
#undef MFMA_HALF

    #pragma unroll
    for (int mi = 0; mi < 8; ++mi) {
        int oc = oc0 + wm * 128 + mi * 16 + lq * 4;
        #pragma unroll
        for (int ni = 0; ni < 4; ++ni) {
            int n = n0 + wn * 64 + ni * 16 + lr;
            #pragma unroll
            for (int v = 0; v < 4; ++v) {
                float r = acc[mi][ni][v] + bias[oc + v];
                out[((size_t)(b * OC + oc + v)) * HW + n] = r;
            }
        }
    }
}

extern "C" void kernel_launch(void* const* d_in, const int* in_sizes, int n_in,
                              void* d_out, int out_size, void* d_ws, size_t ws_size,
                              hipStream_t stream) {
    const float* x      = (const float*)d_in[0];
    const float* style  = (const float*)d_in[1];
    const float* weight = (const float*)d_in[2];
    const float* bias   = (const float*)d_in[3];
    const float* mod_w  = (const float*)d_in[4];
    const float* mod_b  = (const float*)d_in[5];
    float* out = (float*)d_out;

    // ws: s [32KB] | wmod bf16 [75.5MB] | xT bf16 [67.2MB]
    float* s_ws = (float*)d_ws;
    __hip_bfloat16* wmod = (__hip_bfloat16*)((char*)d_ws + 32768);
    __hip_bfloat16* xT   = (__hip_bfloat16*)((char*)d_ws + 32768 + (size_t)16 * 512 * KTOT * 2);

    style_mod_kernel<<<2048, 256, 0, stream>>>(style, mod_w, mod_b, s_ws);
    wmod_kernel<<<512, 256, 0, stream>>>(weight, s_ws, wmod);
    zero_row_kernel<<<16, 256, 0, stream>>>(xT);
    dim3 tgrid(64, 8, 16);
    xpose_kernel<<<tgrid, 256, 0, stream>>>(x, xT);
    conv_kernel<<<512, 512, 0, stream>>>(xT, wmod, bias, out);
}